// Round 8
// baseline (586.517 us; speedup 1.0000x reference)
//
#include <hip/hip_runtime.h>

#define B_SZ 1024
#define F_SZ 512
#define NK   50
#define KD   5
#define C_SZ 250              // NK*KD
#define OUTW 562              // F_SZ + NK
#define PLANE (C_SZ * B_SZ)   // SoA M plane: [col c=k*5+d][row], 256000 floats
#define NT   16               // 16 row-tiles of 64
#define TILE 64
#define NPAIRS 136            // NT*(NT+1)/2 unordered tile pairs
#define PART_ELEMS (NK * NT * B_SZ)   // 819200 floats
#define LOG2E 1.44269504088896340736f

// ---------------------------------------------------------------------------
// K1: fused GEMM + copy. grid 384 x 256.
//  blocks [0,256):   M = x@T scaled by log2e, SoA planes ws2[ks][c][row].
//                    rt = blk&127 (8 rows), ks = blk>>7 (256 f each).
//                    Thread t owns column c = t (<250). x block-uniform ->
//                    s_loads; T coalesced; output 2x float4 per thread.
//  blocks [256,384): copy x rows into out (float2), 8 rows/block.
//                    block 256 also zeroes the per-k completion counters.
// ---------------------------------------------------------------------------
__global__ __launch_bounds__(256) void gemm_copy_kernel(const float* __restrict__ x,
                                                        const float* __restrict__ T,
                                                        float* __restrict__ ws2,
                                                        float* __restrict__ out,
                                                        int* __restrict__ cnt,
                                                        int zero_feat) {
    const int t = threadIdx.x;

    if (blockIdx.x >= 256) {                 // ---- copy path
        const int b = blockIdx.x - 256;      // 0..127
        if (b == 0 && t < 64) cnt[t] = 0;    // zero counters before pair runs
#pragma unroll
        for (int r = 0; r < 8; ++r) {
            const int row = b * 8 + r;
            const float2* src = (const float2*)(x + (size_t)row * F_SZ);
            float2* dst = (float2*)(out + (size_t)row * OUTW);
            dst[t] = src[t];
            if (zero_feat && t < NK) out[(size_t)row * OUTW + F_SZ + t] = 0.0f;
        }
        return;
    }

    // ---- gemm path
    const int rt = blockIdx.x & 127;         // 8-row tile
    const int ks = blockIdx.x >> 7;          // k-split (0,1)
    if (t >= C_SZ) return;                   // no __syncthreads in this path
    const int r0 = rt * 8;
    const int f0 = ks * 256;

    float acc[8] = {0.f, 0.f, 0.f, 0.f, 0.f, 0.f, 0.f, 0.f};
    const float* xp = x + (size_t)r0 * F_SZ + f0;     // block-uniform base
    const float* Tp = T + (size_t)f0 * C_SZ + t;

#pragma unroll 8
    for (int f = 0; f < 256; ++f) {
        const float tv = Tp[(size_t)f * C_SZ];
#pragma unroll
        for (int r = 0; r < 8; ++r)
            acc[r] += xp[r * F_SZ + f] * tv;          // uniform -> s_load
    }

    float* dst = ws2 + ((size_t)(ks * C_SZ + t)) * B_SZ + r0;   // 32B aligned
    float4 lo = make_float4(acc[0] * LOG2E, acc[1] * LOG2E,
                            acc[2] * LOG2E, acc[3] * LOG2E);
    float4 hi = make_float4(acc[4] * LOG2E, acc[5] * LOG2E,
                            acc[6] * LOG2E, acc[7] * LOG2E);
    ((float4*)dst)[0] = lo;
    ((float4*)dst)[1] = hi;
}

// ---------------------------------------------------------------------------
// K2: symmetric pairwise features. grid 6800 = 50 k x 136 tile pairs (ti<=tj,
// 64-row tiles); 256 threads. Each block computes the 64x64 e-block once:
//   pass 1: lane i = t&63, j-quarter jq = t>>6. Row sums accumulate in
//           registers; every e also stored to et[j][i] (LDS, padded).
//   pass 2: column sums (= row sums of et) -> partial for tile tj (skipped
//           on diagonal blocks). Partials: part[k][sp][row], sp = source tile.
// Last block per k (threadfence+counter) folds the 16 partials into out.
// ---------------------------------------------------------------------------
template <bool ATOMIC>
__global__ __launch_bounds__(256) void pair_kernel(const float* __restrict__ ws2,
                                                   float* __restrict__ part,
                                                   float* __restrict__ out,
                                                   int* __restrict__ cnt) {
    // ---- decode block id -> (k, ti, tj), all scalar-uniform
    const int bid = blockIdx.x;
    const int k = bid / NPAIRS;
    int p = bid - k * NPAIRS;
    int ti = 0;
    while (p >= NT - ti) { p -= NT - ti; ++ti; }
    const int tj = ti + p;

    const int t    = threadIdx.x;
    const int lane = t & 63;
    const int jq   = t >> 6;

    __shared__ __align__(16) float qi[KD][TILE];
    __shared__ __align__(16) float qj[KD][TILE];
    __shared__ float et[TILE][TILE + 1];     // padded: b32 access only
    __shared__ float rowp[4][TILE];
    __shared__ float colp[4][TILE];
    __shared__ int   lastFlag;

    const float* pa = ws2 + (size_t)k * KD * B_SZ;   // plane 0, cols k*5..
    const float* pb = pa + (size_t)PLANE;            // plane 1

    if (t < TILE) {                          // stage tile ti (coalesced SoA)
#pragma unroll
        for (int d = 0; d < KD; ++d) {
            const int row = ti * TILE + t;
            qi[d][t] = pa[d * B_SZ + row] + pb[d * B_SZ + row];
        }
    } else if (t < 2 * TILE) {               // stage tile tj
        const int l = t - TILE;
#pragma unroll
        for (int d = 0; d < KD; ++d) {
            const int row = tj * TILE + l;
            qj[d][l] = pa[d * B_SZ + row] + pb[d * B_SZ + row];
        }
    }
    __syncthreads();

    // ---- pass 1: 16 pairs/thread (i = lane, j = jq*16 + 0..15)
    float m0 = qi[0][lane], m1 = qi[1][lane], m2 = qi[2][lane],
          m3 = qi[3][lane], m4 = qi[4][lane];
    float acc = 0.0f;
#pragma unroll
    for (int c4 = 0; c4 < 4; ++c4) {
        const int j0 = jq * 16 + c4 * 4;
        const float4 c0 = *(const float4*)&qj[0][j0];   // broadcast b128
        const float4 c1 = *(const float4*)&qj[1][j0];
        const float4 c2 = *(const float4*)&qj[2][j0];
        const float4 c3 = *(const float4*)&qj[3][j0];
        const float4 c4_ = *(const float4*)&qj[4][j0];
#define PAIR_ONE(C, JOFF)                                                        \
        {                                                                        \
            const float s = __builtin_fabsf(m0 - c0.C)                           \
                          + __builtin_fabsf(m1 - c1.C)                           \
                          + __builtin_fabsf(m2 - c2.C)                           \
                          + __builtin_fabsf(m3 - c3.C)                           \
                          + __builtin_fabsf(m4 - c4_.C);                         \
            const float e = __builtin_amdgcn_exp2f(-s);                          \
            acc += e;                                                            \
            et[j0 + JOFF][lane] = e;                                             \
        }
        PAIR_ONE(x, 0) PAIR_ONE(y, 1) PAIR_ONE(z, 2) PAIR_ONE(w, 3)
#undef PAIR_ONE
    }
    rowp[jq][lane] = acc;
    __syncthreads();

    // ---- pass 2: column sums (rows of et), off-diagonal only
    if (ti != tj) {
        float csum = 0.0f;
#pragma unroll
        for (int e = 0; e < 16; ++e) csum += et[lane][jq * 16 + e];
        colp[jq][lane] = csum;
    }

    // ---- row partial: rows of tile ti, source tile tj
    if (t < TILE) {
        const float r = rowp[0][t] + rowp[1][t] + rowp[2][t] + rowp[3][t];
        const int row = ti * TILE + t;
        if (ATOMIC) atomicAdd(&out[(size_t)row * OUTW + F_SZ + k], r);
        else        part[((size_t)(k * NT + tj)) * B_SZ + row] = r;
    }

    // ---- col partial: rows of tile tj, source tile ti
    if (ti != tj) {
        __syncthreads();
        if (t < TILE) {
            const float c = colp[0][t] + colp[1][t] + colp[2][t] + colp[3][t];
            const int row = tj * TILE + t;
            if (ATOMIC) atomicAdd(&out[(size_t)row * OUTW + F_SZ + k], c);
            else        part[((size_t)(k * NT + ti)) * B_SZ + row] = c;
        }
    }

    // ---- last block for this k folds the 16 partials into out
    if (!ATOMIC) {
        __threadfence();                     // release our partial stores
        __syncthreads();
        if (t == 0) {
            const int old = atomicAdd(&cnt[k], 1);
            lastFlag = (old == NPAIRS - 1);
        }
        __syncthreads();
        if (lastFlag) {
            __threadfence();                 // acquire others' partial stores
#pragma unroll
            for (int q = 0; q < 4; ++q) {
                const int row = t + 256 * q;
                float s = 0.0f;
#pragma unroll
                for (int sp = 0; sp < NT; ++sp)
                    s += part[((size_t)(k * NT + sp)) * B_SZ + row];
                out[(size_t)row * OUTW + F_SZ + k] = s;
            }
        }
    }
}

// ---------------------------------------------------------------------------
extern "C" void kernel_launch(void* const* d_in, const int* in_sizes, int n_in,
                              void* d_out, int out_size, void* d_ws, size_t ws_size,
                              hipStream_t stream) {
    const float* x = (const float*)d_in[0];   // [1024, 512]
    const float* T = (const float*)d_in[1];   // [512, 250]
    float* out = (float*)d_out;               // [1024, 562]
    float* ws2 = (float*)d_ws;                // 2 SoA planes [250][1024]
    float* part = ws2 + 2 * (size_t)PLANE;    // [50][16][1024]
    int*   cnt  = (int*)(part + PART_ELEMS);  // [64]

    const size_t need = (size_t)(2 * PLANE + PART_ELEMS) * 4 + 256;
    const int fast = (ws_size >= need);

    gemm_copy_kernel<<<384, 256, 0, stream>>>(x, T, ws2, out, cnt, fast ? 0 : 1);

    if (fast) {
        pair_kernel<false><<<NK * NPAIRS, 256, 0, stream>>>(ws2, part, out, cnt);
    } else {
        pair_kernel<true><<<NK * NPAIRS, 256, 0, stream>>>(ws2, part, out, cnt);
    }
}

// Round 9
// 35.701 us; speedup vs baseline: 16.4288x; 16.4288x over previous
//
#include <hip/hip_runtime.h>

#define B_SZ 1024
#define F_SZ 512
#define NK   50
#define KD   5
#define C_SZ 250              // NK*KD
#define OUTW 562              // F_SZ + NK
#define PLANE (C_SZ * B_SZ)   // SoA M plane: [col c=k*5+d][row], 256000 floats
#define NT   16               // 16 row-tiles of 64
#define TILE 64
#define NPAIRS 136            // NT*(NT+1)/2 unordered tile pairs
#define PART_ELEMS (NK * NT * B_SZ)   // 819200 floats
#define LOG2E 1.44269504088896340736f

// ---------------------------------------------------------------------------
// K1: fused GEMM + copy. grid 384 x 256.
//  blocks [0,256):   M = x@T scaled by log2e, SoA planes ws2[ks][c][row].
//                    rt = blk&127 (8 rows), ks = blk>>7 (256 f each).
//                    Thread t owns column c = t (<250). x block-uniform ->
//                    s_loads; T coalesced; output 2x float4 per thread.
//  blocks [256,384): copy x rows into out (float2), 8 rows/block.
// ---------------------------------------------------------------------------
__global__ __launch_bounds__(256) void gemm_copy_kernel(const float* __restrict__ x,
                                                        const float* __restrict__ T,
                                                        float* __restrict__ ws2,
                                                        float* __restrict__ out,
                                                        int zero_feat) {
    const int t = threadIdx.x;

    if (blockIdx.x >= 256) {                 // ---- copy path
        const int b = blockIdx.x - 256;      // 0..127
#pragma unroll
        for (int r = 0; r < 8; ++r) {
            const int row = b * 8 + r;
            const float2* src = (const float2*)(x + (size_t)row * F_SZ);
            float2* dst = (float2*)(out + (size_t)row * OUTW);
            dst[t] = src[t];
            if (zero_feat && t < NK) out[(size_t)row * OUTW + F_SZ + t] = 0.0f;
        }
        return;
    }

    // ---- gemm path
    const int rt = blockIdx.x & 127;         // 8-row tile
    const int ks = blockIdx.x >> 7;          // k-split (0,1)
    if (t >= C_SZ) return;                   // no __syncthreads in this path
    const int r0 = rt * 8;
    const int f0 = ks * 256;

    float acc[8] = {0.f, 0.f, 0.f, 0.f, 0.f, 0.f, 0.f, 0.f};
    const float* xp = x + (size_t)r0 * F_SZ + f0;     // block-uniform base
    const float* Tp = T + (size_t)f0 * C_SZ + t;

#pragma unroll 8
    for (int f = 0; f < 256; ++f) {
        const float tv = Tp[(size_t)f * C_SZ];
#pragma unroll
        for (int r = 0; r < 8; ++r)
            acc[r] += xp[r * F_SZ + f] * tv;          // uniform -> s_load
    }

    float* dst = ws2 + ((size_t)(ks * C_SZ + t)) * B_SZ + r0;   // 32B aligned
    float4 lo = make_float4(acc[0] * LOG2E, acc[1] * LOG2E,
                            acc[2] * LOG2E, acc[3] * LOG2E);
    float4 hi = make_float4(acc[4] * LOG2E, acc[5] * LOG2E,
                            acc[6] * LOG2E, acc[7] * LOG2E);
    ((float4*)dst)[0] = lo;
    ((float4*)dst)[1] = hi;
}

// ---------------------------------------------------------------------------
// K2: symmetric pairwise features. grid 6800 = 50 k x 136 tile pairs (ti<=tj,
// 64-row tiles); 256 threads. Each block computes the 64x64 e-block ONCE:
//   pass 1: lane i = t&63, j-quarter jq = t>>6. Row sums accumulate in
//           registers; every e also stored to et[j][i] (LDS, +1 pad).
//   pass 2: column sums (= rows of et) -> partial for tile tj (skipped on
//           diagonal blocks). Partials: part[k][sp][row], sp = source tile;
//           each (sp,row) cell is written by exactly one block.
// NO fences, NO counters, NO atomics on the fast path (round-8 lesson:
// per-block device-scope fences serialize at ~87 ns each = 13x regression).
// ---------------------------------------------------------------------------
template <bool ATOMIC>
__global__ __launch_bounds__(256) void pair_kernel(const float* __restrict__ ws2,
                                                   float* __restrict__ part,
                                                   float* __restrict__ out) {
    // ---- decode block id -> (k, ti, tj), all scalar-uniform
    const int bid = blockIdx.x;
    const int k = bid / NPAIRS;
    int p = bid - k * NPAIRS;
    int ti = 0;
    while (p >= NT - ti) { p -= NT - ti; ++ti; }
    const int tj = ti + p;

    const int t    = threadIdx.x;
    const int lane = t & 63;
    const int jq   = t >> 6;

    __shared__ __align__(16) float qi[KD][TILE];
    __shared__ __align__(16) float qj[KD][TILE];
    __shared__ float et[TILE][TILE + 1];     // padded: b32 access both ways
    __shared__ float rowp[4][TILE];
    __shared__ float colp[4][TILE];

    const float* pa = ws2 + (size_t)k * KD * B_SZ;   // plane 0, cols k*5..
    const float* pb = pa + (size_t)PLANE;            // plane 1

    if (t < TILE) {                          // stage tile ti (coalesced SoA)
#pragma unroll
        for (int d = 0; d < KD; ++d) {
            const int row = ti * TILE + t;
            qi[d][t] = pa[d * B_SZ + row] + pb[d * B_SZ + row];
        }
    } else if (t < 2 * TILE) {               // stage tile tj
        const int l = t - TILE;
#pragma unroll
        for (int d = 0; d < KD; ++d) {
            const int row = tj * TILE + l;
            qj[d][l] = pa[d * B_SZ + row] + pb[d * B_SZ + row];
        }
    }
    __syncthreads();

    // ---- pass 1: 16 pairs/thread (i = lane, j = jq*16 + 0..15)
    float m0 = qi[0][lane], m1 = qi[1][lane], m2 = qi[2][lane],
          m3 = qi[3][lane], m4 = qi[4][lane];
    float acc = 0.0f;
#pragma unroll
    for (int c4 = 0; c4 < 4; ++c4) {
        const int j0 = jq * 16 + c4 * 4;
        const float4 c0 = *(const float4*)&qj[0][j0];   // broadcast b128
        const float4 c1 = *(const float4*)&qj[1][j0];
        const float4 c2 = *(const float4*)&qj[2][j0];
        const float4 c3 = *(const float4*)&qj[3][j0];
        const float4 c4_ = *(const float4*)&qj[4][j0];
#define PAIR_ONE(C, JOFF)                                                        \
        {                                                                        \
            const float s = __builtin_fabsf(m0 - c0.C)                           \
                          + __builtin_fabsf(m1 - c1.C)                           \
                          + __builtin_fabsf(m2 - c2.C)                           \
                          + __builtin_fabsf(m3 - c3.C)                           \
                          + __builtin_fabsf(m4 - c4_.C);                         \
            const float e = __builtin_amdgcn_exp2f(-s);                          \
            acc += e;                                                            \
            et[j0 + JOFF][lane] = e;                                             \
        }
        PAIR_ONE(x, 0) PAIR_ONE(y, 1) PAIR_ONE(z, 2) PAIR_ONE(w, 3)
#undef PAIR_ONE
    }
    rowp[jq][lane] = acc;
    __syncthreads();

    // ---- pass 2: column sums (rows of et), off-diagonal only
    if (ti != tj) {
        float csum = 0.0f;
#pragma unroll
        for (int e = 0; e < 16; ++e) csum += et[lane][jq * 16 + e];
        colp[jq][lane] = csum;
    }

    // ---- row partial: rows of tile ti, source tile tj
    if (t < TILE) {
        const float r = rowp[0][t] + rowp[1][t] + rowp[2][t] + rowp[3][t];
        const int row = ti * TILE + t;
        if (ATOMIC) atomicAdd(&out[(size_t)row * OUTW + F_SZ + k], r);
        else        part[((size_t)(k * NT + tj)) * B_SZ + row] = r;
    }

    // ---- col partial: rows of tile tj, source tile ti
    if (ti != tj) {
        __syncthreads();
        if (t < TILE) {
            const float c = colp[0][t] + colp[1][t] + colp[2][t] + colp[3][t];
            const int row = tj * TILE + t;
            if (ATOMIC) atomicAdd(&out[(size_t)row * OUTW + F_SZ + k], c);
            else        part[((size_t)(k * NT + ti)) * B_SZ + row] = c;
        }
    }
}

// ---------------------------------------------------------------------------
// K3: fold the 16 tile-source partials into out. grid 200 x 256.
// Reads coalesced (lanes contiguous in row); L2-resident.
// ---------------------------------------------------------------------------
__global__ __launch_bounds__(256) void reduce_kernel(const float* __restrict__ part,
                                                     float* __restrict__ out) {
    const int k = blockIdx.x >> 2;
    const int i = ((blockIdx.x & 3) << 8) | threadIdx.x;
    float s = 0.0f;
#pragma unroll
    for (int sp = 0; sp < NT; ++sp)
        s += part[((size_t)(k * NT + sp)) * B_SZ + i];
    out[(size_t)i * OUTW + F_SZ + k] = s;
}

// ---------------------------------------------------------------------------
extern "C" void kernel_launch(void* const* d_in, const int* in_sizes, int n_in,
                              void* d_out, int out_size, void* d_ws, size_t ws_size,
                              hipStream_t stream) {
    const float* x = (const float*)d_in[0];   // [1024, 512]
    const float* T = (const float*)d_in[1];   // [512, 250]
    float* out = (float*)d_out;               // [1024, 562]
    float* ws2 = (float*)d_ws;                // 2 SoA planes [250][1024]
    float* part = ws2 + 2 * (size_t)PLANE;    // [50][16][1024]

    const size_t need = (size_t)(2 * PLANE + PART_ELEMS) * 4;   // 5.3 MB
    const int fast = (ws_size >= need);

    gemm_copy_kernel<<<384, 256, 0, stream>>>(x, T, ws2, out, fast ? 0 : 1);

    if (fast) {
        pair_kernel<false><<<NK * NPAIRS, 256, 0, stream>>>(ws2, part, out);
        reduce_kernel<<<200, 256, 0, stream>>>(part, out);
    } else {
        pair_kernel<true><<<NK * NPAIRS, 256, 0, stream>>>(ws2, nullptr, out);
    }
}